// Round 15
// baseline (550.828 us; speedup 1.0000x reference)
//
#include <hip/hip_runtime.h>
#include <hip/hip_bf16.h>
#include <stdint.h>

typedef short s16x8 __attribute__((ext_vector_type(8)));
typedef short s16x4 __attribute__((ext_vector_type(4)));
typedef float f32x4 __attribute__((ext_vector_type(4)));

#define H_ 16
#define DH 32
#define NTOK 49
#define CDIM 512
#define SCALE 0.17677669529663687f

typedef const __attribute__((address_space(1))) uint32_t* gas_ptr;
typedef __attribute__((address_space(3))) uint32_t* las_ptr;
#define GLL16(g, l) __builtin_amdgcn_global_load_lds((gas_ptr)(g), (las_ptr)(l), 16, 0, 0)

__device__ __forceinline__ short f2bf(float f){
  union { __bf16 h; short s; } u;
  u.h = (__bf16)f;
  return u.s;
}

__device__ __forceinline__ s16x8 pack8(float4 a, float4 b){
  s16x8 r;
  r[0]=f2bf(a.x); r[1]=f2bf(a.y); r[2]=f2bf(a.z); r[3]=f2bf(a.w);
  r[4]=f2bf(b.x); r[5]=f2bf(b.y); r[6]=f2bf(b.z); r[7]=f2bf(b.w);
  return r;
}

// bijective XCD swizzle (m204)
__device__ __forceinline__ int xcd_swz(int orig, int nwg){
  int q = nwg >> 3, r = nwg & 7;
  int x = orig & 7, idx = orig >> 3;
  return (x < r ? x*(q+1) : r*(q+1) + (x - r)*q) + idx;
}

// ---------------------------------------------------------------------------
// Prep kernels (run once)
// ---------------------------------------------------------------------------
__global__ void prep_wq_kernel(const float* __restrict__ w, const float* __restrict__ b,
                               short* __restrict__ wq, float* __restrict__ pb)
{
  int t = blockIdx.x*256 + threadIdx.x;        // [0, 1536*64)
  int jp = t >> 6, kg = t & 63;
  int s = jp >> 9, h = (jp >> 5) & 15, d = jp & 31;
  int srow = h*96 + d*3 + s;
  float fac = (s == 0) ? SCALE : 1.0f;
  const float* wr = w + (size_t)srow*CDIM + kg*8;
  float4 a = *(const float4*)wr;
  float4 c = *(const float4*)(wr+4);
  a.x*=fac; a.y*=fac; a.z*=fac; a.w*=fac;
  c.x*=fac; c.y*=fac; c.z*=fac; c.w*=fac;
  ((s16x8*)(wq + (size_t)jp*CDIM))[kg] = pack8(a,c);
  if (kg == 0) pb[jp] = b[srow]*fac;
}

__global__ void prep_wo_kernel(const float* __restrict__ w, short* __restrict__ wo)
{
  int t = blockIdx.x*256 + threadIdx.x;        // [0, 512*64)
  int j = t >> 6, kg = t & 63;
  const float* wr = w + (size_t)j*CDIM + kg*8;
  float4 a = *(const float4*)wr;
  float4 c = *(const float4*)(wr+4);
  ((s16x8*)(wo + (size_t)j*CDIM))[kg] = pack8(a,c);
}

// bm[w][h][r*52+c] = mask[w][r][c] + 2 * rp_bias_table[rp_index[r][c]][h]
#define BMSTR 52
#define BMSLAB 2548
__global__ void prep_bm_kernel(const int* __restrict__ idx, const float* __restrict__ tab,
                               const float* __restrict__ mask, float* __restrict__ bm)
{
  int wh = blockIdx.x;
  int w = wh >> 4, h = wh & 15;
  const float* mw = mask + (size_t)w*2401;
  float* o = bm + (size_t)wh*BMSLAB;
  for (int i = threadIdx.x; i < 2401; i += 256){
    int r = i / 49, c = i - r*49;
    o[r*BMSTR + c] = mw[i] + 2.0f*tab[idx[i]*H_ + h];
  }
}

__global__ void cvt_kernel(const float* __restrict__ src, short* __restrict__ dst, int n8)
{
  int i = blockIdx.x*blockDim.x + threadIdx.x;
  int stride = gridDim.x*blockDim.x;
  for (; i < n8; i += stride){
    float4 a = ((const float4*)src)[2*i];
    float4 b = ((const float4*)src)[2*i+1];
    ((s16x8*)dst)[i] = pack8(a,b);
  }
}

// ---------------------------------------------------------------------------
// 128x128 GEMM (round-10 frozen, best-known): BK=64, 256 thr (4 waves 2x2),
// dbuf 64KB LDS (2 blocks/CU), T4 counted-vmcnt 1-deep, T2 both-sides XOR
// swizzle (0 conflicts verified), T5 setprio. K = 512 (8 K-tiles).
// EPI 0: qkv scatter [bl][h][n][d]. EPI 1: f32 out + bias.
// ---------------------------------------------------------------------------
template<int EPI>
__global__ __launch_bounds__(256)
void gemm128(const short* __restrict__ A, const short* __restrict__ Bm,
             const float* __restrict__ pb,
             short* __restrict__ Q, short* __restrict__ Kd, short* __restrict__ V,
             float* __restrict__ outF, int ntiles, int nwg, int b0)
{
  __shared__ __align__(16) short As[2][8192];
  __shared__ __align__(16) short Bs[2][8192];
  const int tid = threadIdx.x, w = tid >> 6, l = tid & 63;
  const int wg = xcd_swz(blockIdx.x, nwg);
  const int mt = wg / ntiles, jt = wg % ntiles;
  const int wr = w >> 1, wc = w & 1, lg = l >> 4, lc = l & 15;

  const int srow = w*8 + (l >> 3);
  const int sbyte = ((l & 7) ^ (l >> 3)) << 4;
  const char* gA = (const char*)A  + ((size_t)(mt*128 + srow))*1024 + sbyte;
  const char* gB = (const char*)Bm + ((size_t)(jt*128 + srow))*1024 + sbyte;

  f32x4 acc[4][4];
  #pragma unroll
  for (int i=0;i<4;++i)
    #pragma unroll
    for (int j=0;j<4;++j) acc[i][j] = (f32x4){0.f,0.f,0.f,0.f};

  #pragma unroll
  for (int i=0;i<4;++i){
    GLL16(gA + i*32768, (char*)As[0] + i*4096 + w*1024);
    GLL16(gB + i*32768, (char*)Bs[0] + i*4096 + w*1024);
  }

  int buf = 0;
  for (int kt=0; kt<8; ++kt){
    if (kt < 7){
      const char* ga2 = gA + (kt+1)*128;
      const char* gb2 = gB + (kt+1)*128;
      #pragma unroll
      for (int i=0;i<4;++i){
        GLL16(ga2 + i*32768, (char*)As[buf^1] + i*4096 + w*1024);
        GLL16(gb2 + i*32768, (char*)Bs[buf^1] + i*4096 + w*1024);
      }
      asm volatile("s_waitcnt vmcnt(8)" ::: "memory");   // stage(t) landed
    } else {
      asm volatile("s_waitcnt vmcnt(0)" ::: "memory");
    }
    __builtin_amdgcn_s_barrier();

    const char* pA = (const char*)As[buf];
    const char* pB = (const char*)Bs[buf];
    #pragma unroll
    for (int kk=0; kk<2; ++kk){
      const int kbyte = (kk*64 + lg*16) ^ ((lc & 7) << 4);
      s16x8 af[4], bf_[4];
      #pragma unroll
      for (int i=0;i<4;++i)
        af[i]  = *(const s16x8*)(pA + (wr*64 + i*16 + lc)*128 + kbyte);
      #pragma unroll
      for (int j=0;j<4;++j)
        bf_[j] = *(const s16x8*)(pB + (wc*64 + j*16 + lc)*128 + kbyte);
      __builtin_amdgcn_s_setprio(1);
      #pragma unroll
      for (int i=0;i<4;++i)
        #pragma unroll
        for (int j=0;j<4;++j)
          acc[i][j] = __builtin_amdgcn_mfma_f32_16x16x32_bf16(af[i], bf_[j], acc[i][j], 0,0,0);
      __builtin_amdgcn_s_setprio(0);
    }
    __builtin_amdgcn_s_barrier();
    buf ^= 1;
  }

  const int cb = jt*128 + wc*64;
  if (EPI == 0){
    const int s_sel = cb >> 9;
    short* dst = (s_sel==0) ? Q : (s_sel==1 ? Kd : V);
    float bv[4]; int hj[4], dj[4];
    #pragma unroll
    for (int j=0;j<4;++j){
      int cc = cb + j*16 + lc;
      bv[j] = pb[cc];
      hj[j] = (cc >> 5) & 15;
      dj[j] = cc & 31;
    }
    #pragma unroll
    for (int i=0;i<4;++i){
      #pragma unroll
      for (int r=0;r<4;++r){
        int grow = mt*128 + wr*64 + i*16 + lg*4 + r;
        int bl = grow / 49;
        int n  = grow - bl*49;
        #pragma unroll
        for (int j=0;j<4;++j)
          dst[(((size_t)bl*H_ + hj[j])*NTOK + n)*DH + dj[j]] = f2bf(acc[i][j][r] + bv[j]);
      }
    }
  } else {
    float bv[4];
    #pragma unroll
    for (int j=0;j<4;++j) bv[j] = pb[cb + j*16 + lc];
    #pragma unroll
    for (int i=0;i<4;++i){
      #pragma unroll
      for (int r=0;r<4;++r){
        int grow = mt*128 + wr*64 + i*16 + lg*4 + r;
        size_t o = ((size_t)(b0*NTOK) + grow)*CDIM + cb;
        #pragma unroll
        for (int j=0;j<4;++j)
          outF[o + j*16 + lc] = acc[i][j][r] + bv[j];
      }
    }
  }
}

// ---------------------------------------------------------------------------
// Attention (round-13 structure: swapped QK^T softmax, float4 bias reads,
// packed P-stores) + T5 setprio around MFMA clusters + fused cvt tail.
// ---------------------------------------------------------------------------
template<int GROUPED>
__global__ __launch_bounds__(256)
void attn_kernel(const short* __restrict__ Q, const short* __restrict__ Kt,
                 const short* __restrict__ V, const float* __restrict__ bm,
                 short* __restrict__ AO, int b0, int nW,
                 const float* __restrict__ xsrc, short* __restrict__ xdst, int n8)
{
  __shared__ __align__(16) short P[4][64][72];
  __shared__ __align__(16) float bmL[BMSLAB];
  const int tid = threadIdx.x, wv = tid >> 6, lane = tid & 63;
  const int lg = lane >> 4, lc = lane & 15;
  const int h = blockIdx.x & 15, rest = blockIdx.x >> 4;

  int bl, widx;
  if (GROUPED){
    widx = rest % nW;
    int g4 = rest / nW;
    bl = widx + (g4*4 + wv)*nW;
  } else {
    bl = rest*4 + wv;
    widx = (b0 + bl) % nW;
  }

  const short* q = Q  + ((size_t)bl*H_ + h)*NTOK*DH;
  const short* k = Kt + ((size_t)bl*H_ + h)*NTOK*DH;
  const short* v = V  + ((size_t)bl*H_ + h)*NTOK*DH;

  if (GROUPED){
    const float4* bmg = (const float4*)(bm + ((size_t)widx*H_ + h)*BMSLAB);
    #pragma unroll
    for (int i=0;i<3;++i){
      int s = tid + i*256;
      if (s < BMSLAB/4) ((float4*)bmL)[s] = bmg[s];
    }
  }

  s16x8 qa[4], kb[4];
  #pragma unroll
  for (int t=0;t<4;++t){
    int r = t*16 + lc; if (r > 48) r = 48;
    qa[t] = *(const s16x8*)(q + r*DH + lg*8);
    kb[t] = *(const s16x8*)(k + r*DH + lg*8);
  }
  f32x4 S2[4][4];
  #pragma unroll
  for (int i=0;i<4;++i)
    #pragma unroll
    for (int j=0;j<4;++j) S2[i][j] = (f32x4){0.f,0.f,0.f,0.f};
  __builtin_amdgcn_s_setprio(1);
  #pragma unroll
  for (int i=0;i<4;++i)
    #pragma unroll
    for (int j=0;j<4;++j)
      S2[i][j] = __builtin_amdgcn_mfma_f32_16x16x32_bf16(kb[i], qa[j], S2[i][j], 0,0,0);
  __builtin_amdgcn_s_setprio(0);

  if (GROUPED) __syncthreads();
  const float* bmh = GROUPED ? bmL : (bm + ((size_t)widx*H_ + h)*BMSLAB);

  const int k0 = lg*4;
  #pragma unroll
  for (int j=0;j<4;++j){
    const int qcol = j*16 + lc;
    const int qc = (qcol > 48) ? 48 : qcol;
    #pragma unroll
    for (int i=0;i<4;++i){
      float4 b4 = *(const float4*)(bmh + qc*BMSTR + i*16 + k0);
      int kbase = i*16 + k0;
      S2[i][j][0] = (kbase + 0 <= 48) ? S2[i][j][0] + b4.x : -1.0e30f;
      S2[i][j][1] = (kbase + 1 <= 48) ? S2[i][j][1] + b4.y : -1.0e30f;
      S2[i][j][2] = (kbase + 2 <= 48) ? S2[i][j][2] + b4.z : -1.0e30f;
      S2[i][j][3] = (kbase + 3 <= 48) ? S2[i][j][3] + b4.w : -1.0e30f;
    }
    float mx = S2[0][j][0];
    #pragma unroll
    for (int i=0;i<4;++i)
      #pragma unroll
      for (int r=0;r<4;++r) mx = fmaxf(mx, S2[i][j][r]);
    mx = fmaxf(mx, __shfl_xor(mx, 16, 64));
    mx = fmaxf(mx, __shfl_xor(mx, 32, 64));
    float sum = 0.f;
    #pragma unroll
    for (int i=0;i<4;++i)
      #pragma unroll
      for (int r=0;r<4;++r){
        float e = __expf(S2[i][j][r] - mx);
        S2[i][j][r] = e;
        sum += e;
      }
    sum += __shfl_xor(sum, 16, 64);
    sum += __shfl_xor(sum, 32, 64);
    const float rs = 1.0f / sum;
    #pragma unroll
    for (int i=0;i<4;++i){
      s16x4 pk;
      pk[0] = f2bf(S2[i][j][0] * rs);
      pk[1] = f2bf(S2[i][j][1] * rs);
      pk[2] = f2bf(S2[i][j][2] * rs);
      pk[3] = f2bf(S2[i][j][3] * rs);
      *(s16x4*)&P[wv][qcol][i*16 + k0] = pk;
    }
  }

  s16x8 vb[2][2];
  #pragma unroll
  for (int kt=0;kt<2;++kt)
    #pragma unroll
    for (int nt=0;nt<2;++nt){
      s16x8 t;
      #pragma unroll
      for (int e=0;e<8;++e){
        int kk = kt*32 + lg*8 + e; if (kk > 48) kk = 48;
        t[e] = v[kk*DH + nt*16 + lc];
      }
      vb[kt][nt] = t;
    }
  f32x4 O[4][2];
  #pragma unroll
  for (int i=0;i<4;++i){ O[i][0] = (f32x4){0.f,0.f,0.f,0.f}; O[i][1] = (f32x4){0.f,0.f,0.f,0.f}; }
  #pragma unroll
  for (int i=0;i<4;++i){
    #pragma unroll
    for (int kt=0;kt<2;++kt){
      s16x8 pa = *(const s16x8*)&P[wv][i*16 + lc][kt*32 + lg*8];
      __builtin_amdgcn_s_setprio(1);
      #pragma unroll
      for (int nt=0;nt<2;++nt)
        O[i][nt] = __builtin_amdgcn_mfma_f32_16x16x32_bf16(pa, vb[kt][nt], O[i][nt], 0,0,0);
      __builtin_amdgcn_s_setprio(0);
    }
  }
  #pragma unroll
  for (int i=0;i<4;++i)
    #pragma unroll
    for (int r=0;r<4;++r){
      int row = i*16 + lg*4 + r;
      if (row < 49){
        size_t o = ((size_t)bl*NTOK + row)*CDIM + h*DH;
        AO[o + lc]      = f2bf(O[i][0][r]);
        AO[o + 16 + lc] = f2bf(O[i][1][r]);
      }
    }

  // fused cvt tail: convert next chunk's x slab (n8==0 for last chunk)
  for (int i2 = blockIdx.x*256 + tid; i2 < n8; i2 += gridDim.x*256){
    float4 a = ((const float4*)xsrc)[2*i2];
    float4 b = ((const float4*)xsrc)[2*i2+1];
    ((s16x8*)xdst)[i2] = pack8(a,b);
  }
}

extern "C" void kernel_launch(void* const* d_in, const int* in_sizes, int n_in,
                              void* d_out, int out_size, void* d_ws, size_t ws_size,
                              hipStream_t stream)
{
  const float* x      = (const float*)d_in[0];
  const float* qkv_w  = (const float*)d_in[1];
  const float* qkv_b  = (const float*)d_in[2];
  const int*   rp_idx = (const int*)d_in[3];
  const float* rp_tab = (const float*)d_in[4];
  const float* out_w  = (const float*)d_in[5];
  const float* out_b  = (const float*)d_in[6];
  const float* mask   = (const float*)d_in[7];
  const int nW = in_sizes[7] / (NTOK*NTOK);
  float* out = (float*)d_out;

  char* base = (char*)d_ws;
  size_t off = 0;
  auto alloc = [&](size_t bytes)->char*{
    char* p = base + off;
    off = (off + bytes + 255) & ~(size_t)255;
    return p;
  };
  float* bm  = (float*)alloc((size_t)nW*H_*BMSLAB*4);
  short* wq  = (short*)alloc((size_t)1536*CDIM*2);
  float* pbq = (float*)alloc(1536*4);
  short* wo  = (short*)alloc((size_t)CDIM*CDIM*2);

  int CB = 1024;
  while (CB > 128){
    size_t need = off + 5*(size_t)CB*50176;
    if (need <= ws_size) break;
    CB >>= 1;
  }
  short* xb = (short*)alloc((size_t)CB*50176);
  short* Q  = (short*)alloc((size_t)CB*50176);
  short* K  = (short*)alloc((size_t)CB*50176);
  short* V  = (short*)alloc((size_t)CB*50176);
  short* AO = (short*)alloc((size_t)CB*50176);

  hipLaunchKernelGGL(prep_bm_kernel, dim3(nW*H_), dim3(256), 0, stream,
                     rp_idx, rp_tab, mask, bm);
  hipLaunchKernelGGL(prep_wq_kernel, dim3(1536*64/256), dim3(256), 0, stream,
                     qkv_w, qkv_b, wq, pbq);
  hipLaunchKernelGGL(prep_wo_kernel, dim3(512*64/256), dim3(256), 0, stream,
                     out_w, wo);

  const bool grouped = (CB % (4*nW)) == 0;
  const int nchunk = 2048 / CB;
  const int mtiles = CB*NTOK/128;
  const int n8 = CB*3136;

  // chunk 0's x converted standalone; chunk c+1 converted inside attn(c)
  hipLaunchKernelGGL(cvt_kernel, dim3(2048), dim3(256), 0, stream,
                     x, xb, n8);

  for (int c=0; c<nchunk; ++c){
    int b0 = c*CB;
    hipLaunchKernelGGL((gemm128<0>), dim3(mtiles*12), dim3(256), 0, stream,
                       xb, wq, pbq, Q, K, V, (float*)nullptr, 12, mtiles*12, b0);
    const float* xnext = x + (size_t)(c+1)*CB*NTOK*CDIM;
    const int n8next = (c+1 < nchunk) ? n8 : 0;
    if (grouped)
      hipLaunchKernelGGL((attn_kernel<1>), dim3(CB*4), dim3(256), 0, stream,
                         Q, K, V, bm, AO, b0, nW, xnext, xb, n8next);
    else
      hipLaunchKernelGGL((attn_kernel<0>), dim3(CB*4), dim3(256), 0, stream,
                         Q, K, V, bm, AO, b0, nW, xnext, xb, n8next);
    hipLaunchKernelGGL((gemm128<1>), dim3(mtiles*4), dim3(256), 0, stream,
                       AO, wo, (float*)out_b, (short*)nullptr, (short*)nullptr, (short*)nullptr,
                       out, 4, mtiles*4, b0);
  }
}

// Round 16
// 511.793 us; speedup vs baseline: 1.0763x; 1.0763x over previous
//
#include <hip/hip_runtime.h>
#include <hip/hip_bf16.h>
#include <stdint.h>

typedef short s16x8 __attribute__((ext_vector_type(8)));
typedef float f32x4 __attribute__((ext_vector_type(4)));

#define H_ 16
#define DH 32
#define NTOK 49
#define CDIM 512
#define SCALE 0.17677669529663687f

typedef const __attribute__((address_space(1))) uint32_t* gas_ptr;
typedef __attribute__((address_space(3))) uint32_t* las_ptr;
#define GLL16(g, l) __builtin_amdgcn_global_load_lds((gas_ptr)(g), (las_ptr)(l), 16, 0, 0)

__device__ __forceinline__ short f2bf(float f){
  union { __bf16 h; short s; } u;
  u.h = (__bf16)f;
  return u.s;
}

__device__ __forceinline__ s16x8 pack8(float4 a, float4 b){
  s16x8 r;
  r[0]=f2bf(a.x); r[1]=f2bf(a.y); r[2]=f2bf(a.z); r[3]=f2bf(a.w);
  r[4]=f2bf(b.x); r[5]=f2bf(b.y); r[6]=f2bf(b.z); r[7]=f2bf(b.w);
  return r;
}

// bijective XCD swizzle (m204)
__device__ __forceinline__ int xcd_swz(int orig, int nwg){
  int q = nwg >> 3, r = nwg & 7;
  int x = orig & 7, idx = orig >> 3;
  return (x < r ? x*(q+1) : r*(q+1) + (x - r)*q) + idx;
}

// ---------------------------------------------------------------------------
// Prep kernels (run once)
// ---------------------------------------------------------------------------
__global__ void prep_wq_kernel(const float* __restrict__ w, const float* __restrict__ b,
                               short* __restrict__ wq, float* __restrict__ pb)
{
  int t = blockIdx.x*256 + threadIdx.x;        // [0, 1536*64)
  int jp = t >> 6, kg = t & 63;
  int s = jp >> 9, h = (jp >> 5) & 15, d = jp & 31;
  int srow = h*96 + d*3 + s;
  float fac = (s == 0) ? SCALE : 1.0f;
  const float* wr = w + (size_t)srow*CDIM + kg*8;
  float4 a = *(const float4*)wr;
  float4 c = *(const float4*)(wr+4);
  a.x*=fac; a.y*=fac; a.z*=fac; a.w*=fac;
  c.x*=fac; c.y*=fac; c.z*=fac; c.w*=fac;
  ((s16x8*)(wq + (size_t)jp*CDIM))[kg] = pack8(a,c);
  if (kg == 0) pb[jp] = b[srow]*fac;
}

__global__ void prep_wo_kernel(const float* __restrict__ w, short* __restrict__ wo)
{
  int t = blockIdx.x*256 + threadIdx.x;        // [0, 512*64)
  int j = t >> 6, kg = t & 63;
  const float* wr = w + (size_t)j*CDIM + kg*8;
  float4 a = *(const float4*)wr;
  float4 c = *(const float4*)(wr+4);
  ((s16x8*)(wo + (size_t)j*CDIM))[kg] = pack8(a,c);
}

// bm[w][h][r*50+c] = mask[w][r][c] + 2 * rp_bias_table[rp_index[r][c]][h]
#define BMSTR 50
#define BMSLAB 2464
__global__ void prep_bm_kernel(const int* __restrict__ idx, const float* __restrict__ tab,
                               const float* __restrict__ mask, float* __restrict__ bm)
{
  int wh = blockIdx.x;
  int w = wh >> 4, h = wh & 15;
  const float* mw = mask + (size_t)w*2401;
  float* o = bm + (size_t)wh*BMSLAB;
  for (int i = threadIdx.x; i < 2401; i += 256){
    int r = i / 49, c = i - r*49;
    o[r*BMSTR + c] = mw[i] + 2.0f*tab[idx[i]*H_ + h];
  }
}

__global__ void cvt_kernel(const float* __restrict__ src, short* __restrict__ dst, int n8)
{
  int i = blockIdx.x*blockDim.x + threadIdx.x;
  int stride = gridDim.x*blockDim.x;
  for (; i < n8; i += stride){
    float4 a = ((const float4*)src)[2*i];
    float4 b = ((const float4*)src)[2*i+1];
    ((s16x8*)dst)[i] = pack8(a,b);
  }
}

// ---------------------------------------------------------------------------
// 128x128 GEMM (round-10 frozen): BK=64, 256 thr (4 waves 2x2), dbuf 64KB LDS,
// T4 counted-vmcnt (STAGE(t+1) -> vmcnt(8) -> barrier -> compute -> barrier),
// T2 both-sides XOR swizzle (0 conflicts verified), T5 setprio.
// EPI 0: qkv scatter [bl][h][n][d]. EPI 1: f32 out + bias.
// ---------------------------------------------------------------------------
template<int EPI>
__global__ __launch_bounds__(256)
void gemm128(const short* __restrict__ A, const short* __restrict__ Bm,
             const float* __restrict__ pb,
             short* __restrict__ Q, short* __restrict__ Kd, short* __restrict__ V,
             float* __restrict__ outF, int ntiles, int nwg, int b0)
{
  __shared__ __align__(16) short As[2][8192];
  __shared__ __align__(16) short Bs[2][8192];
  const int tid = threadIdx.x, w = tid >> 6, l = tid & 63;
  const int wg = xcd_swz(blockIdx.x, nwg);
  const int mt = wg / ntiles, jt = wg % ntiles;
  const int wr = w >> 1, wc = w & 1, lg = l >> 4, lc = l & 15;

  const int srow = w*8 + (l >> 3);
  const int sbyte = ((l & 7) ^ (l >> 3)) << 4;
  const char* gA = (const char*)A  + ((size_t)(mt*128 + srow))*1024 + sbyte;
  const char* gB = (const char*)Bm + ((size_t)(jt*128 + srow))*1024 + sbyte;

  f32x4 acc[4][4];
  #pragma unroll
  for (int i=0;i<4;++i)
    #pragma unroll
    for (int j=0;j<4;++j) acc[i][j] = (f32x4){0.f,0.f,0.f,0.f};

  #pragma unroll
  for (int i=0;i<4;++i){
    GLL16(gA + i*32768, (char*)As[0] + i*4096 + w*1024);
    GLL16(gB + i*32768, (char*)Bs[0] + i*4096 + w*1024);
  }

  int buf = 0;
  for (int kt=0; kt<8; ++kt){
    if (kt < 7){
      const char* ga2 = gA + (kt+1)*128;
      const char* gb2 = gB + (kt+1)*128;
      #pragma unroll
      for (int i=0;i<4;++i){
        GLL16(ga2 + i*32768, (char*)As[buf^1] + i*4096 + w*1024);
        GLL16(gb2 + i*32768, (char*)Bs[buf^1] + i*4096 + w*1024);
      }
      asm volatile("s_waitcnt vmcnt(8)" ::: "memory");   // stage(t) landed
    } else {
      asm volatile("s_waitcnt vmcnt(0)" ::: "memory");
    }
    __builtin_amdgcn_s_barrier();

    const char* pA = (const char*)As[buf];
    const char* pB = (const char*)Bs[buf];
    #pragma unroll
    for (int kk=0; kk<2; ++kk){
      const int kbyte = (kk*64 + lg*16) ^ ((lc & 7) << 4);
      s16x8 af[4], bf_[4];
      #pragma unroll
      for (int i=0;i<4;++i)
        af[i]  = *(const s16x8*)(pA + (wr*64 + i*16 + lc)*128 + kbyte);
      #pragma unroll
      for (int j=0;j<4;++j)
        bf_[j] = *(const s16x8*)(pB + (wc*64 + j*16 + lc)*128 + kbyte);
      __builtin_amdgcn_s_setprio(1);
      #pragma unroll
      for (int i=0;i<4;++i)
        #pragma unroll
        for (int j=0;j<4;++j)
          acc[i][j] = __builtin_amdgcn_mfma_f32_16x16x32_bf16(af[i], bf_[j], acc[i][j], 0,0,0);
      __builtin_amdgcn_s_setprio(0);
    }
    __builtin_amdgcn_s_barrier();
    buf ^= 1;
  }

  const int cb = jt*128 + wc*64;
  if (EPI == 0){
    const int s_sel = cb >> 9;
    short* dst = (s_sel==0) ? Q : (s_sel==1 ? Kd : V);
    float bv[4]; int hj[4], dj[4];
    #pragma unroll
    for (int j=0;j<4;++j){
      int cc = cb + j*16 + lc;
      bv[j] = pb[cc];
      hj[j] = (cc >> 5) & 15;
      dj[j] = cc & 31;
    }
    #pragma unroll
    for (int i=0;i<4;++i){
      #pragma unroll
      for (int r=0;r<4;++r){
        int grow = mt*128 + wr*64 + i*16 + lg*4 + r;
        int bl = grow / 49;
        int n  = grow - bl*49;
        #pragma unroll
        for (int j=0;j<4;++j)
          dst[(((size_t)bl*H_ + hj[j])*NTOK + n)*DH + dj[j]] = f2bf(acc[i][j][r] + bv[j]);
      }
    }
  } else {
    float bv[4];
    #pragma unroll
    for (int j=0;j<4;++j) bv[j] = pb[cb + j*16 + lc];
    #pragma unroll
    for (int i=0;i<4;++i){
      #pragma unroll
      for (int r=0;r<4;++r){
        int grow = mt*128 + wr*64 + i*16 + lg*4 + r;
        size_t o = ((size_t)(b0*NTOK) + grow)*CDIM + cb;
        #pragma unroll
        for (int j=0;j<4;++j)
          outF[o + j*16 + lc] = acc[i][j][r] + bv[j];
      }
    }
  }
}

// ---------------------------------------------------------------------------
// Attention with SWAPPED QK^T softmax (round-10 frozen).
// ---------------------------------------------------------------------------
template<int GROUPED>
__global__ __launch_bounds__(256)
void attn_kernel(const short* __restrict__ Q, const short* __restrict__ Kt,
                 const short* __restrict__ V, const float* __restrict__ bm,
                 short* __restrict__ AO, int b0, int nW)
{
  __shared__ __align__(16) short P[4][64][72];
  __shared__ __align__(16) float bmL[BMSLAB];
  const int tid = threadIdx.x, wv = tid >> 6, lane = tid & 63;
  const int lg = lane >> 4, lc = lane & 15;
  const int h = blockIdx.x & 15, rest = blockIdx.x >> 4;

  int bl, widx;
  if (GROUPED){
    widx = rest % nW;
    int g4 = rest / nW;
    bl = widx + (g4*4 + wv)*nW;
  } else {
    bl = rest*4 + wv;
    widx = (b0 + bl) % nW;
  }

  const short* q = Q  + ((size_t)bl*H_ + h)*NTOK*DH;
  const short* k = Kt + ((size_t)bl*H_ + h)*NTOK*DH;
  const short* v = V  + ((size_t)bl*H_ + h)*NTOK*DH;

  if (GROUPED){
    const float4* bmg = (const float4*)(bm + ((size_t)widx*H_ + h)*BMSLAB);
    #pragma unroll
    for (int i=0;i<3;++i){
      int s = tid + i*256;
      if (s < BMSLAB/4) ((float4*)bmL)[s] = bmg[s];
    }
  }

  s16x8 qa[4], kb[4];
  #pragma unroll
  for (int t=0;t<4;++t){
    int r = t*16 + lc; if (r > 48) r = 48;
    qa[t] = *(const s16x8*)(q + r*DH + lg*8);
    kb[t] = *(const s16x8*)(k + r*DH + lg*8);
  }
  // S^T tiles: S2[i][j] = S^T[k = i*16+lg*4+reg][qcol = j*16+lc]
  f32x4 S2[4][4];
  #pragma unroll
  for (int i=0;i<4;++i)
    #pragma unroll
    for (int j=0;j<4;++j) S2[i][j] = (f32x4){0.f,0.f,0.f,0.f};
  #pragma unroll
  for (int i=0;i<4;++i)
    #pragma unroll
    for (int j=0;j<4;++j)
      S2[i][j] = __builtin_amdgcn_mfma_f32_16x16x32_bf16(kb[i], qa[j], S2[i][j], 0,0,0);

  if (GROUPED) __syncthreads();
  const float* bmh = GROUPED ? bmL : (bm + ((size_t)widx*H_ + h)*BMSLAB);

  const int k0 = lg*4;
  #pragma unroll
  for (int j=0;j<4;++j){
    const int qcol = j*16 + lc;
    const int qc = (qcol > 48) ? 48 : qcol;
    #pragma unroll
    for (int i=0;i<4;++i){
      const float* bp = bmh + qc*BMSTR + i*16 + k0;
      float2 b01 = *(const float2*)(bp);
      float2 b23 = *(const float2*)(bp + 2);
      int kbase = i*16 + k0;
      S2[i][j][0] = (kbase + 0 <= 48) ? S2[i][j][0] + b01.x : -1.0e30f;
      S2[i][j][1] = (kbase + 1 <= 48) ? S2[i][j][1] + b01.y : -1.0e30f;
      S2[i][j][2] = (kbase + 2 <= 48) ? S2[i][j][2] + b23.x : -1.0e30f;
      S2[i][j][3] = (kbase + 3 <= 48) ? S2[i][j][3] + b23.y : -1.0e30f;
    }
    float mx = S2[0][j][0];
    #pragma unroll
    for (int i=0;i<4;++i)
      #pragma unroll
      for (int r=0;r<4;++r) mx = fmaxf(mx, S2[i][j][r]);
    mx = fmaxf(mx, __shfl_xor(mx, 16, 64));
    mx = fmaxf(mx, __shfl_xor(mx, 32, 64));
    float sum = 0.f;
    #pragma unroll
    for (int i=0;i<4;++i)
      #pragma unroll
      for (int r=0;r<4;++r){
        float e = __expf(S2[i][j][r] - mx);
        S2[i][j][r] = e;
        sum += e;
      }
    sum += __shfl_xor(sum, 16, 64);
    sum += __shfl_xor(sum, 32, 64);
    const float rs = 1.0f / sum;
    #pragma unroll
    for (int i=0;i<4;++i)
      #pragma unroll
      for (int r=0;r<4;++r)
        P[wv][qcol][i*16 + k0 + r] = f2bf(S2[i][j][r] * rs);
  }

  s16x8 vb[2][2];
  #pragma unroll
  for (int kt=0;kt<2;++kt)
    #pragma unroll
    for (int nt=0;nt<2;++nt){
      s16x8 t;
      #pragma unroll
      for (int e=0;e<8;++e){
        int kk = kt*32 + lg*8 + e; if (kk > 48) kk = 48;
        t[e] = v[kk*DH + nt*16 + lc];
      }
      vb[kt][nt] = t;
    }
  f32x4 O[4][2];
  #pragma unroll
  for (int i=0;i<4;++i){ O[i][0] = (f32x4){0.f,0.f,0.f,0.f}; O[i][1] = (f32x4){0.f,0.f,0.f,0.f}; }
  #pragma unroll
  for (int i=0;i<4;++i){
    #pragma unroll
    for (int kt=0;kt<2;++kt){
      s16x8 pa = *(const s16x8*)&P[wv][i*16 + lc][kt*32 + lg*8];
      #pragma unroll
      for (int nt=0;nt<2;++nt)
        O[i][nt] = __builtin_amdgcn_mfma_f32_16x16x32_bf16(pa, vb[kt][nt], O[i][nt], 0,0,0);
    }
  }
  #pragma unroll
  for (int i=0;i<4;++i)
    #pragma unroll
    for (int r=0;r<4;++r){
      int row = i*16 + lg*4 + r;
      if (row < 49){
        size_t o = ((size_t)bl*NTOK + row)*CDIM + h*DH;
        AO[o + lc]      = f2bf(O[i][0][r]);
        AO[o + 16 + lc] = f2bf(O[i][1][r]);
      }
    }
}

extern "C" void kernel_launch(void* const* d_in, const int* in_sizes, int n_in,
                              void* d_out, int out_size, void* d_ws, size_t ws_size,
                              hipStream_t stream)
{
  const float* x      = (const float*)d_in[0];
  const float* qkv_w  = (const float*)d_in[1];
  const float* qkv_b  = (const float*)d_in[2];
  const int*   rp_idx = (const int*)d_in[3];
  const float* rp_tab = (const float*)d_in[4];
  const float* out_w  = (const float*)d_in[5];
  const float* out_b  = (const float*)d_in[6];
  const float* mask   = (const float*)d_in[7];
  const int nW = in_sizes[7] / (NTOK*NTOK);
  float* out = (float*)d_out;

  char* base = (char*)d_ws;
  size_t off = 0;
  auto alloc = [&](size_t bytes)->char*{
    char* p = base + off;
    off = (off + bytes + 255) & ~(size_t)255;
    return p;
  };
  float* bm  = (float*)alloc((size_t)nW*H_*BMSLAB*4);
  short* wq  = (short*)alloc((size_t)1536*CDIM*2);
  float* pbq = (float*)alloc(1536*4);
  short* wo  = (short*)alloc((size_t)CDIM*CDIM*2);

  int CB = 1024;
  while (CB > 128){
    size_t need = off + 5*(size_t)CB*50176;
    if (need <= ws_size) break;
    CB >>= 1;
  }
  short* xb = (short*)alloc((size_t)CB*50176);
  short* Q  = (short*)alloc((size_t)CB*50176);
  short* K  = (short*)alloc((size_t)CB*50176);
  short* V  = (short*)alloc((size_t)CB*50176);
  short* AO = (short*)alloc((size_t)CB*50176);

  hipLaunchKernelGGL(prep_bm_kernel, dim3(nW*H_), dim3(256), 0, stream,
                     rp_idx, rp_tab, mask, bm);
  hipLaunchKernelGGL(prep_wq_kernel, dim3(1536*64/256), dim3(256), 0, stream,
                     qkv_w, qkv_b, wq, pbq);
  hipLaunchKernelGGL(prep_wo_kernel, dim3(512*64/256), dim3(256), 0, stream,
                     out_w, wo);

  const bool grouped = (CB % (4*nW)) == 0;
  const int nchunk = 2048 / CB;
  const int mtiles = CB*NTOK/128;
  const int n8 = CB*3136;
  for (int c=0; c<nchunk; ++c){
    int b0 = c*CB;
    hipLaunchKernelGGL(cvt_kernel, dim3(2048), dim3(256), 0, stream,
                       x + (size_t)b0*NTOK*CDIM, xb, n8);
    hipLaunchKernelGGL((gemm128<0>), dim3(mtiles*12), dim3(256), 0, stream,
                       xb, wq, pbq, Q, K, V, (float*)nullptr, 12, mtiles*12, b0);
    if (grouped)
      hipLaunchKernelGGL((attn_kernel<1>), dim3(CB*4), dim3(256), 0, stream,
                         Q, K, V, bm, AO, b0, nW);
    else
      hipLaunchKernelGGL((attn_kernel<0>), dim3(CB*4), dim3(256), 0, stream,
                         Q, K, V, bm, AO, b0, nW);
    hipLaunchKernelGGL((gemm128<1>), dim3(mtiles*4), dim3(256), 0, stream,
                       AO, wo, (float*)out_b, (short*)nullptr, (short*)nullptr, (short*)nullptr,
                       out, 4, mtiles*4, b0);
  }
}